// Round 1
// baseline (3129.769 us; speedup 1.0000x reference)
//
#include <hip/hip_runtime.h>
#include <stdint.h>

#define DEV __device__ __forceinline__

typedef short bf16x8 __attribute__((ext_vector_type(8)));
typedef float f32x4 __attribute__((ext_vector_type(4)));

DEV unsigned short f2bf(float f) {
  union { float f; uint32_t u; } v; v.f = f;
  return (unsigned short)((v.u + 0x7fffu + ((v.u >> 16) & 1u)) >> 16);
}

DEV void gload16(const void* g, void* lds) {
  __builtin_amdgcn_global_load_lds(
      (const __attribute__((address_space(1))) int*)(uintptr_t)g,
      (__attribute__((address_space(3))) int*)(uintptr_t)lds, 16, 0, 0);
}

// ---------------- generic NT GEMM: C[M,N] = A[M,K] * B[N,K]^T + bias ----------------
// 128x128 tile, BK=32, 4 waves each 64x64 (4x4 frags of 16x16x32 bf16 MFMA).
template <typename OutT>
__global__ __launch_bounds__(256) void gemm_nt(
    const unsigned short* __restrict__ A, int lda,
    const unsigned short* __restrict__ B, int ldb,
    OutT* __restrict__ C, int ldc,
    OutT* __restrict__ C2, int ldc2,
    const float* __restrict__ bias,
    int K, int Nreal)
{
  __shared__ alignas(16) unsigned short Asm[128 * 32];
  __shared__ alignas(16) unsigned short Bsm[128 * 32];
  const int tid = threadIdx.x;
  const int wave = tid >> 6, lane = tid & 63;
  const int m0 = blockIdx.x * 128, n0 = blockIdx.y * 128;
  const int wr = wave >> 1, wc = wave & 1;

  f32x4 acc[4][4] = {};

  // staging: 512 chunks of 16B per tile (A and B each); thread covers chunks tid, tid+256
  const int q0 = tid, q1 = tid + 256;
  const unsigned short* Ag0 = A + (size_t)(m0 + (q0 >> 2)) * lda + (q0 & 3) * 8;
  const unsigned short* Ag1 = A + (size_t)(m0 + (q1 >> 2)) * lda + (q1 & 3) * 8;
  const unsigned short* Bg0 = B + (size_t)(n0 + (q0 >> 2)) * ldb + (q0 & 3) * 8;
  const unsigned short* Bg1 = B + (size_t)(n0 + (q1 >> 2)) * ldb + (q1 & 3) * 8;
  char* As0 = (char*)Asm + wave * 1024;  char* As1 = As0 + 4096;
  char* Bs0 = (char*)Bsm + wave * 1024;  char* Bs1 = Bs0 + 4096;

  const int ra = wr * 64 + (lane & 15);
  const int rb = wc * 64 + (lane & 15);
  const int kb = (lane >> 4) * 16;  // byte offset of K-subblock within 64B row

  for (int k0 = 0; k0 < K; k0 += 32) {
    gload16(Ag0 + k0, As0);
    gload16(Ag1 + k0, As1);
    gload16(Bg0 + k0, Bs0);
    gload16(Bg1 + k0, Bs1);
    __syncthreads();
    bf16x8 af[4], bfr[4];
#pragma unroll
    for (int i = 0; i < 4; ++i)
      af[i] = *(const bf16x8*)((const char*)Asm + (ra + i * 16) * 64 + kb);
#pragma unroll
    for (int i = 0; i < 4; ++i)
      bfr[i] = *(const bf16x8*)((const char*)Bsm + (rb + i * 16) * 64 + kb);
#pragma unroll
    for (int mi = 0; mi < 4; ++mi)
#pragma unroll
      for (int ni = 0; ni < 4; ++ni)
        acc[mi][ni] = __builtin_amdgcn_mfma_f32_16x16x32_bf16(af[mi], bfr[ni], acc[mi][ni], 0, 0, 0);
    __syncthreads();
  }

  const int row0 = m0 + wr * 64 + (lane >> 4) * 4;
  const int col0 = n0 + wc * 64 + (lane & 15);
#pragma unroll
  for (int mi = 0; mi < 4; ++mi) {
#pragma unroll
    for (int ni = 0; ni < 4; ++ni) {
      const int col = col0 + ni * 16;
      if (col >= Nreal) continue;
      const float bs = bias ? bias[col] : 0.f;
#pragma unroll
      for (int r = 0; r < 4; ++r) {
        const int row = row0 + mi * 16 + r;
        const float v = acc[mi][ni][r] + bs;
        if constexpr (sizeof(OutT) == 2) {
          ((unsigned short*)C)[(size_t)row * ldc + col] = f2bf(v);
          if (C2) ((unsigned short*)C2)[(size_t)row * ldc2 + col] = f2bf(v);
        } else {
          ((float*)C)[(size_t)row * ldc + col] = v;
          if (C2) ((float*)C2)[(size_t)row * ldc2 + col] = v;
        }
      }
    }
  }
}

// ---------------- one LSTM timestep, fused gates ----------------
// grid = 16 WGs; WG j owns d-chunk [j*32, j*32+32). Tile cols = [4 gates][32 d]:
// tile col c -> W_hh row (c>>5)*512 + j*32 + (c&31). Epilogue: lane holds i/f/g/o
// for same (b,d) in acc[mi][2g+p] -> gate math fully in-register.
__global__ __launch_bounds__(256) void lstm_step(
    const unsigned short* __restrict__ hprev, int ldh,
    const unsigned short* __restrict__ Whh,
    const float* __restrict__ xpt, int ldxp,
    float* __restrict__ cst,
    unsigned short* __restrict__ hout, int ldho)
{
  __shared__ alignas(16) unsigned short Asm[128 * 32];
  __shared__ alignas(16) unsigned short Bsm[128 * 32];
  const int tid = threadIdx.x;
  const int wave = tid >> 6, lane = tid & 63;
  const int j = blockIdx.x;

  f32x4 acc[2][8] = {};

  const int q0 = tid, q1 = tid + 256;
  const unsigned short* Ag0 = hprev + (size_t)(q0 >> 2) * ldh + (q0 & 3) * 8;
  const unsigned short* Ag1 = hprev + (size_t)(q1 >> 2) * ldh + (q1 & 3) * 8;
  const int rb0 = q0 >> 2, rb1 = q1 >> 2;
  const unsigned short* Bg0 = Whh + (size_t)((rb0 >> 5) * 512 + j * 32 + (rb0 & 31)) * 512 + (q0 & 3) * 8;
  const unsigned short* Bg1 = Whh + (size_t)((rb1 >> 5) * 512 + j * 32 + (rb1 & 31)) * 512 + (q1 & 3) * 8;
  char* As0 = (char*)Asm + wave * 1024;  char* As1 = As0 + 4096;
  char* Bs0 = (char*)Bsm + wave * 1024;  char* Bs1 = Bs0 + 4096;

  const int kb = (lane >> 4) * 16;
  for (int k0 = 0; k0 < 512; k0 += 32) {
    gload16(Ag0 + k0, As0);
    gload16(Ag1 + k0, As1);
    gload16(Bg0 + k0, Bs0);
    gload16(Bg1 + k0, Bs1);
    __syncthreads();
    bf16x8 af[2], bfr[8];
#pragma unroll
    for (int i = 0; i < 2; ++i)
      af[i] = *(const bf16x8*)((const char*)Asm + (wave * 32 + i * 16 + (lane & 15)) * 64 + kb);
#pragma unroll
    for (int i = 0; i < 8; ++i)
      bfr[i] = *(const bf16x8*)((const char*)Bsm + (i * 16 + (lane & 15)) * 64 + kb);
#pragma unroll
    for (int mi = 0; mi < 2; ++mi)
#pragma unroll
      for (int ni = 0; ni < 8; ++ni)
        acc[mi][ni] = __builtin_amdgcn_mfma_f32_16x16x32_bf16(af[mi], bfr[ni], acc[mi][ni], 0, 0, 0);
    __syncthreads();
  }

#pragma unroll
  for (int mi = 0; mi < 2; ++mi) {
#pragma unroll
    for (int r = 0; r < 4; ++r) {
      const int b = wave * 32 + mi * 16 + (lane >> 4) * 4 + r;
      const float* xr = xpt + (size_t)b * ldxp;
#pragma unroll
      for (int p = 0; p < 2; ++p) {
        const int d = j * 32 + p * 16 + (lane & 15);
        const float iv = acc[mi][0 + p][r] + xr[d];
        const float fv = acc[mi][2 + p][r] + xr[512 + d];
        const float gv = acc[mi][4 + p][r] + xr[1024 + d];
        const float ov = acc[mi][6 + p][r] + xr[1536 + d];
        const float co = cst[b * 512 + d];
        const float si = 1.f / (1.f + __expf(-iv));
        const float sf = 1.f / (1.f + __expf(-fv));
        const float so = 1.f / (1.f + __expf(-ov));
        const float cn = sf * co + si * tanhf(gv);
        const float hn = so * tanhf(cn);
        cst[b * 512 + d] = cn;
        hout[(size_t)b * ldho + d] = f2bf(hn);
      }
    }
  }
}

// ---------------- small helpers ----------------
__global__ void cast_bf16(const float* __restrict__ in, unsigned short* __restrict__ out,
                          long nreal, long ntot) {
  for (long i = (long)blockIdx.x * blockDim.x + threadIdx.x; i < ntot;
       i += (long)gridDim.x * blockDim.x)
    out[i] = (i < nreal) ? f2bf(in[i]) : (unsigned short)0;
}

__global__ void gather_rows(const int* __restrict__ ix, const unsigned short* __restrict__ emb,
                            unsigned short* __restrict__ x) {
  const int row = blockIdx.x;
  const int e = ix[row];
  const uint4* s = (const uint4*)(emb + (size_t)e * 512);
  uint4* d = (uint4*)(x + (size_t)row * 512);
  d[threadIdx.x] = s[threadIdx.x];
}

// ---------------- host ----------------
extern "C" void kernel_launch(void* const* d_in, const int* in_sizes, int n_in,
                              void* d_out, int out_size, void* d_ws, size_t ws_size,
                              hipStream_t stream) {
  (void)in_sizes; (void)n_in; (void)out_size; (void)ws_size;
  const float* img    = (const float*)d_in[0];
  const int*   ix     = (const int*)d_in[1];
  const float* emb    = (const float*)d_in[2];
  const float* Wih1f  = (const float*)d_in[3];   // W_init_h1
  const float* bih1   = (const float*)d_in[4];
  const float* Wic1f  = (const float*)d_in[5];
  const float* bic1   = (const float*)d_in[6];
  const float* Wih2f  = (const float*)d_in[7];
  const float* bih2   = (const float*)d_in[8];
  const float* Wic2f  = (const float*)d_in[9];
  const float* bic2   = (const float*)d_in[10];
  const float* Wihl1  = (const float*)d_in[11];  // W_ih1
  const float* Whhl1  = (const float*)d_in[12];
  const float* b1     = (const float*)d_in[13];
  const float* Wihl2  = (const float*)d_in[14];
  const float* Whhl2  = (const float*)d_in[15];
  const float* b2     = (const float*)d_in[16];
  const float* Wv1    = (const float*)d_in[17];
  const float* bv1    = (const float*)d_in[18];
  const float* Wo1    = (const float*)d_in[19];
  const float* bo1    = (const float*)d_in[20];
  const float* Wv2    = (const float*)d_in[21];
  const float* bv2    = (const float*)d_in[22];
  const float* Wo2    = (const float*)d_in[23];
  const float* bo2    = (const float*)d_in[24];
  const float* Wlog   = (const float*)d_in[25];
  const float* blog   = (const float*)d_in[26];
  float* out = (float*)d_out;

  char* p = (char*)d_ws;
  auto al = [&](size_t bytes) { char* r = p; p += (bytes + 255) & ~(size_t)255; return r; };
  unsigned short* emb_b  = (unsigned short*)al((size_t)10000 * 512 * 2);
  unsigned short* Wih1_b = (unsigned short*)al((size_t)2048 * 512 * 2);
  unsigned short* Whh1_b = (unsigned short*)al((size_t)2048 * 512 * 2);
  unsigned short* Wih2_b = (unsigned short*)al((size_t)2048 * 1024 * 2);
  unsigned short* Whh2_b = (unsigned short*)al((size_t)2048 * 512 * 2);
  unsigned short* Wv1_b  = (unsigned short*)al((size_t)512 * 512 * 2);
  unsigned short* Wo1_b  = (unsigned short*)al((size_t)512 * 512 * 2);
  unsigned short* Wv2_b  = (unsigned short*)al((size_t)512 * 512 * 2);
  unsigned short* Wo2_b  = (unsigned short*)al((size_t)512 * 512 * 2);
  unsigned short* Wlog_b = (unsigned short*)al((size_t)10112 * 1536 * 2);  // zero-padded rows
  unsigned short* Wh1i_b = (unsigned short*)al((size_t)512 * 2048 * 2);
  unsigned short* Wc1i_b = (unsigned short*)al((size_t)512 * 2048 * 2);
  unsigned short* Wh2i_b = (unsigned short*)al((size_t)512 * 2048 * 2);
  unsigned short* Wc2i_b = (unsigned short*)al((size_t)512 * 2048 * 2);
  unsigned short* img_b  = (unsigned short*)al((size_t)128 * 2048 * 2);
  unsigned short* x_b    = (unsigned short*)al((size_t)8192 * 512 * 2);
  float*          xp     = (float*)al((size_t)8192 * 2048 * 4);           // shared xp1/xp2
  unsigned short* cat1   = (unsigned short*)al((size_t)8192 * 1024 * 2);  // [h1s | attn1]
  unsigned short* out3   = (unsigned short*)al((size_t)8192 * 1536 * 2);  // [h2s | attn1 | attn2]
  unsigned short* vtmp   = (unsigned short*)al((size_t)8192 * 512 * 2);
  unsigned short* h01    = (unsigned short*)al((size_t)128 * 512 * 2);
  unsigned short* h02    = (unsigned short*)al((size_t)128 * 512 * 2);
  float*          c1st   = (float*)al((size_t)128 * 512 * 4);
  float*          c2st   = (float*)al((size_t)128 * 512 * 4);

  auto cast = [&](const float* s, unsigned short* d, long nreal, long ntot) {
    cast_bf16<<<512, 256, 0, stream>>>(s, d, nreal, ntot);
  };
  cast(img,   img_b,  (long)128 * 2048,  (long)128 * 2048);
  cast(emb,   emb_b,  (long)10000 * 512, (long)10000 * 512);
  cast(Wihl1, Wih1_b, (long)2048 * 512,  (long)2048 * 512);
  cast(Whhl1, Whh1_b, (long)2048 * 512,  (long)2048 * 512);
  cast(Wihl2, Wih2_b, (long)2048 * 1024, (long)2048 * 1024);
  cast(Whhl2, Whh2_b, (long)2048 * 512,  (long)2048 * 512);
  cast(Wv1,   Wv1_b,  (long)512 * 512,   (long)512 * 512);
  cast(Wo1,   Wo1_b,  (long)512 * 512,   (long)512 * 512);
  cast(Wv2,   Wv2_b,  (long)512 * 512,   (long)512 * 512);
  cast(Wo2,   Wo2_b,  (long)512 * 512,   (long)512 * 512);
  cast(Wih1f, Wh1i_b, (long)512 * 2048,  (long)512 * 2048);
  cast(Wic1f, Wc1i_b, (long)512 * 2048,  (long)512 * 2048);
  cast(Wih2f, Wh2i_b, (long)512 * 2048,  (long)512 * 2048);
  cast(Wic2f, Wc2i_b, (long)512 * 2048,  (long)512 * 2048);
  cast(Wlog,  Wlog_b, (long)10000 * 1536, (long)10112 * 1536);

  // init states: h (bf16) and c (f32) = img @ W_init^T + b
  gemm_nt<unsigned short><<<dim3(1, 4), 256, 0, stream>>>(
      img_b, 2048, Wh1i_b, 2048, h01, 512, (unsigned short*)nullptr, 0, bih1, 2048, 512);
  gemm_nt<float><<<dim3(1, 4), 256, 0, stream>>>(
      img_b, 2048, Wc1i_b, 2048, c1st, 512, (float*)nullptr, 0, bic1, 2048, 512);
  gemm_nt<unsigned short><<<dim3(1, 4), 256, 0, stream>>>(
      img_b, 2048, Wh2i_b, 2048, h02, 512, (unsigned short*)nullptr, 0, bih2, 2048, 512);
  gemm_nt<float><<<dim3(1, 4), 256, 0, stream>>>(
      img_b, 2048, Wc2i_b, 2048, c2st, 512, (float*)nullptr, 0, bic2, 2048, 512);

  // x = emb[captions_ix]
  gather_rows<<<8192, 64, 0, stream>>>(ix, emb_b, x_b);

  // xp1 = x @ W_ih1^T + b1   [8192, 2048] f32
  gemm_nt<float><<<dim3(64, 16), 256, 0, stream>>>(
      x_b, 512, Wih1_b, 512, xp, 2048, (float*)nullptr, 0, b1, 512, 2048);

  // LSTM1 -> h1s into cat1 cols [0,512)
  for (int t = 0; t < 64; ++t) {
    const unsigned short* hp = t ? cat1 + (size_t)(t - 1) * 1024 : h01;
    const int ldh = t ? 65536 : 512;
    lstm_step<<<16, 256, 0, stream>>>(hp, ldh, Whh1_b, xp + (size_t)t * 2048, 131072,
                                      c1st, cat1 + (size_t)t * 1024, 65536);
  }

  // attn1 = (h1s @ Wv1^T + bv1) @ Wo1^T + bo1 -> cat1 cols [512,1024) and out3 cols [512,1024)
  gemm_nt<unsigned short><<<dim3(64, 4), 256, 0, stream>>>(
      cat1, 1024, Wv1_b, 512, vtmp, 512, (unsigned short*)nullptr, 0, bv1, 512, 512);
  gemm_nt<unsigned short><<<dim3(64, 4), 256, 0, stream>>>(
      vtmp, 512, Wo1_b, 512, cat1 + 512, 1024, out3 + 512, 1536, bo1, 512, 512);

  // xp2 = [h1s|attn1] @ W_ih2^T + b2
  gemm_nt<float><<<dim3(64, 16), 256, 0, stream>>>(
      cat1, 1024, Wih2_b, 1024, xp, 2048, (float*)nullptr, 0, b2, 1024, 2048);

  // LSTM2 -> h2s into out3 cols [0,512)
  for (int t = 0; t < 64; ++t) {
    const unsigned short* hp = t ? out3 + (size_t)(t - 1) * 1536 : h02;
    const int ldh = t ? 98304 : 512;
    lstm_step<<<16, 256, 0, stream>>>(hp, ldh, Whh2_b, xp + (size_t)t * 2048, 131072,
                                      c2st, out3 + (size_t)t * 1536, 98304);
  }

  // attn2 -> out3 cols [1024,1536)
  gemm_nt<unsigned short><<<dim3(64, 4), 256, 0, stream>>>(
      out3, 1536, Wv2_b, 512, vtmp, 512, (unsigned short*)nullptr, 0, bv2, 512, 512);
  gemm_nt<unsigned short><<<dim3(64, 4), 256, 0, stream>>>(
      vtmp, 512, Wo2_b, 512, out3 + 1024, 1536, (unsigned short*)nullptr, 0, bo2, 512, 512);

  // logits = out3 @ W_logits^T + b_logits  [8192, 10000] f32
  gemm_nt<float><<<dim3(64, 79), 256, 0, stream>>>(
      out3, 1536, Wlog_b, 1536, out, 10000, (float*)nullptr, 0, blog, 1536, 10000);
}